// Round 1
// baseline (635.643 us; speedup 1.0000x reference)
//
#include <hip/hip_runtime.h>
#include <math.h>

typedef float f32x4 __attribute__((ext_vector_type(4)));

// Problem constants: B=64, N=17, T=512, C=64, H=4, DK=16
#define SLAB 32768           // per-(b,n) elems = T*C
#define BSLAB 557056         // per-b elems = N*T*C

__device__ __forceinline__ float gelu_exact(float x) {
  return 0.5f * x * (1.0f + erff(x * 0.7071067811865475f));
}

// ---------------------------------------------------------------------------
// K12: fused GEMM + GAT. One block per bt = b*512 + t.
// GEMM: hs[n][o] = sum_c xs[n][c] * W[o][c], computed in-block with W row
// o=lane held in 16 f32x4 registers (W is 16 KB, L1/L2 resident). Waves split
// the 17 rows (wave w: n = w, w+4, w+8, w+12; wave 0 also n=16).
// Then the GAT attention (identical to the verified k_gat) and writes
//   g = h*scale + h0  (to workspace)   and the permuted residual resP:
//   resP[b, m/64, t, m%64] = x[b, m%17, t, m/17],  m = n*64+c.
// LDS pitch 68 (not 65): 68 words = 272 B, keeps f32x4 row reads 16B-aligned;
// all scalar access phases stay <=2-way (free) on banks.
// ---------------------------------------------------------------------------
__global__ __launch_bounds__(256) void k_gatgemm(const float* __restrict__ X,
                                                 const float* __restrict__ W,
                                                 const int* __restrict__ adj,
                                                 const float* __restrict__ avec,
                                                 float* __restrict__ g,
                                                 float* __restrict__ resP) {
  const int bt = blockIdx.x;
  const int b = bt >> 9, t = bt & 511;
  const int tid = threadIdx.x;
  const int lane = tid & 63, wv = tid >> 6;

  __shared__ float xs[17 * 68];   // h0 tile (X)
  __shared__ float hs[17 * 68];   // h tile (computed GEMM output)
  __shared__ float sv[17 * 4], tv[17 * 4], scalev[17 * 4];
  __shared__ float alpha[17 * 17 * 4];
  __shared__ float av[32];
  __shared__ int adjs[17 * 17];

  const long base = (long)b * BSLAB + (long)t * 64;

  // stage X[b,:,t,:] (coalesced: 64 consecutive lanes = one 256B n-row)
  for (int idx = tid; idx < 1088; idx += 256) {
    int n = idx >> 6, c = idx & 63;
    xs[n * 68 + c] = X[base + (long)n * SLAB + c];
  }
  if (tid < 32) av[tid] = avec[tid];
  for (int idx = tid; idx < 289; idx += 256) adjs[idx] = adj[b * 289 + idx];

  // W row (o = lane) into registers: 16 f32x4 = 64 VGPRs, freed after GEMM
  f32x4 wr[16];
  {
    const float* wrow = W + lane * 64;
#pragma unroll
    for (int k = 0; k < 16; ++k) wr[k] = *(const f32x4*)(wrow + k * 4);
  }
  __syncthreads();

  // ---- GEMM: hs[n][lane] = xs[n][:] . W[lane][:] ----
  {
    auto dotrow = [&](int n) {
      float acc = 0.f;
#pragma unroll
      for (int c4 = 0; c4 < 16; ++c4) {
        f32x4 xv = *(const f32x4*)(xs + n * 68 + c4 * 4);  // broadcast read
        acc = fmaf(xv.x, wr[c4].x, acc);
        acc = fmaf(xv.y, wr[c4].y, acc);
        acc = fmaf(xv.z, wr[c4].z, acc);
        acc = fmaf(xv.w, wr[c4].w, acc);
      }
      hs[n * 68 + lane] = acc;   // banks (4n+lane)%32 -> 2-way, free
    };
    dotrow(wv);
    dotrow(wv + 4);
    dotrow(wv + 8);
    dotrow(wv + 12);
    if (wv == 0) dotrow(16);
  }
  __syncthreads();

  // ---- GAT attention (identical structure to verified k_gat) ----
  if (tid < 68) {
    int n = tid >> 2, h = tid & 3;
    float s = 0.f, tt = 0.f;
#pragma unroll
    for (int d = 0; d < 16; ++d) {
      float hv = hs[n * 68 + h * 16 + d];
      s += hv * av[d];
      tt += hv * av[16 + d];
    }
    sv[n * 4 + h] = s;
    tv[n * 4 + h] = tt;
  }
  __syncthreads();

  if (tid < 68) {
    int i = tid >> 2, h = tid & 3;
    float si = sv[i * 4 + h];
    float e[17];
    float mx = -3.4e38f;
#pragma unroll
    for (int j = 0; j < 17; ++j) {
      float v = si + tv[j * 4 + h];
      v = (v >= 0.f) ? v : 0.2f * v;           // leaky_relu(0.2)
      if (adjs[i * 17 + j] == 0) v += -1e9f;   // mask bias after lrelu
      e[j] = v;
      mx = fmaxf(mx, v);
    }
    float sum = 0.f;
#pragma unroll
    for (int j = 0; j < 17; ++j) { float p = expf(e[j] - mx); e[j] = p; sum += p; }
    float inv = 1.0f / sum;
#pragma unroll
    for (int j = 0; j < 17; ++j) alpha[(i * 17 + j) * 4 + h] = e[j] * inv;
  }
  __syncthreads();

  if (tid < 68) {
    int j = tid >> 2, h = tid & 3;
    float sc = 0.f;
#pragma unroll
    for (int i = 0; i < 17; ++i) sc += alpha[(i * 17 + j) * 4 + h];
    scalev[j * 4 + h] = sc;
  }
  __syncthreads();

  for (int idx = tid; idx < 1088; idx += 256) {
    int n = idx >> 6, c = idx & 63;
    long a = base + (long)n * SLAB + c;
    g[a] = hs[n * 68 + c] * scalev[n * 4 + (c >> 4)] + xs[n * 68 + c];
    resP[a] = xs[(idx % 17) * 68 + (idx / 17)];
  }
}

// ---------------------------------------------------------------------------
// K3: TCN (2x causal depthwise conv + eval-BN + exact GELU) + transpose +
// residual add. One block per (b,n). g's per-(b,n) flat [T,C] block IS the
// conv layout [c'=idx>>9][t'=idx&511].
// Restructured: 4 quarter-phases of 128 t's; EVERY thread (cc=tid>>2, q=tid&3)
// convolves t' in [h*128 + q*32, +32) each phase (lead-in of 6 g-values from
// global). LDS L[64][133] fp32 = 34 KB -> 4 blocks/CU (was 66 KB -> 2).
// Write index + (t_local>>5) skew puts the 4 q-lanes of a channel in 4
// distinct banks (conflict-free writes); read side recomputes the same skew.
// resP lives in d_out; final out overwrites it same-thread same-address.
// ---------------------------------------------------------------------------
__global__ __launch_bounds__(256) void k_tcn(const float* __restrict__ g,
                                             const float* __restrict__ w1,
                                             const float* __restrict__ gamma1,
                                             const float* __restrict__ beta1,
                                             const float* __restrict__ w2,
                                             const float* __restrict__ gamma2,
                                             const float* __restrict__ beta2,
                                             float* __restrict__ out) {
  const int bn = blockIdx.x;
  const int tid = threadIdx.x;
  const int cc = tid >> 2, q = tid & 3;

  __shared__ float L[64 * 133];   // 34048 B

  const long gbase = (long)bn * SLAB + cc * 512;
  const long obase = (long)bn * SLAB;

  const float bnmul = 0.9999950000374997f;  // 1/sqrt(1+1e-5)
  const float w10 = w1[cc * 3 + 0], w11 = w1[cc * 3 + 1], w12 = w1[cc * 3 + 2];
  const float w20 = w2[cc * 3 + 0], w21 = w2[cc * 3 + 1], w22 = w2[cc * 3 + 2];
  const float bs1 = gamma1[cc] * bnmul, bb1 = beta1[cc];
  const float bs2 = gamma2[cc] * bnmul, bb2 = beta2[cc];

  for (int h = 0; h < 4; ++h) {
    const int t0 = h * 128 + q * 32;

    // lead-in state: gm* = raw g, zm* = conv1+BN+GELU outputs (z[t<0] == 0
    // exactly: reference zero-pads z before conv2)
    float gm1 = 0.f, gm2 = 0.f;
    float zm1 = 0.f, zm2 = 0.f, zm3 = 0.f, zm4 = 0.f;
    if (t0 > 0) {
      float gg[6];
#pragma unroll
      for (int k = 0; k < 6; ++k) gg[k] = g[gbase + (t0 - 6 + k)];
      zm4 = gelu_exact((w10 * gg[0] + w11 * gg[1] + w12 * gg[2]) * bs1 + bb1);
      zm3 = gelu_exact((w10 * gg[1] + w11 * gg[2] + w12 * gg[3]) * bs1 + bb1);
      zm2 = gelu_exact((w10 * gg[2] + w11 * gg[3] + w12 * gg[4]) * bs1 + bb1);
      zm1 = gelu_exact((w10 * gg[3] + w11 * gg[4] + w12 * gg[5]) * bs1 + bb1);
      gm2 = gg[4];
      gm1 = gg[5];
    }

    for (int blk = 0; blk < 8; ++blk) {
      f32x4 gv4 = *(const f32x4*)(g + gbase + t0 + blk * 4);
#pragma unroll
      for (int j = 0; j < 4; ++j) {
        float gv = gv4[j];
        float z = gelu_exact((w10 * gm2 + w11 * gm1 + w12 * gv) * bs1 + bb1);
        float y = gelu_exact((w20 * zm4 + w21 * zm2 + w22 * z) * bs2 + bb2);
        int tl = q * 32 + blk * 4 + j;          // local t within phase
        L[cc * 133 + tl + q] = y;               // +q == +(tl>>5) skew
        gm2 = gm1; gm1 = gv;
        zm4 = zm3; zm3 = zm2; zm2 = zm1; zm1 = z;
      }
    }
    __syncthreads();

    // transpose + residual for out flat range [h*8192, h*8192+8192)
    for (int k = 0; k < 8; ++k) {
      int f4 = h * 2048 + tid + k * 256;
      int flat = f4 * 4;
      int t = flat >> 6, c0 = flat & 63;
      int tl = t - h * 128;
      int skew = tl >> 5;
      f32x4 r4 = *(const f32x4*)(out + obase + flat);
      f32x4 o4;
#pragma unroll
      for (int j = 0; j < 4; ++j)
        o4[j] = L[(c0 + j) * 133 + tl + skew] + r4[j];
      *(f32x4*)(out + obase + flat) = o4;
    }
    __syncthreads();
  }
}

// ---------------------------------------------------------------------------
extern "C" void kernel_launch(void* const* d_in, const int* in_sizes, int n_in,
                              void* d_out, int out_size, void* d_ws, size_t ws_size,
                              hipStream_t stream) {
  const float* x = (const float*)d_in[0];
  const int* adj = (const int*)d_in[1];
  const float* W = (const float*)d_in[2];
  const float* avec = (const float*)d_in[3];
  const float* w1 = (const float*)d_in[4];
  const float* gamma1 = (const float*)d_in[5];
  const float* beta1 = (const float*)d_in[6];
  const float* w2 = (const float*)d_in[7];
  const float* gamma2 = (const float*)d_in[8];
  const float* beta2 = (const float*)d_in[9];

  float* g = (float*)d_ws;       // 142.6 MB scratch: GAT output / TCN input
  float* out = (float*)d_out;    // resP written by K12, consumed in-place by K3

  k_gatgemm<<<32768, 256, 0, stream>>>(x, W, adj, avec, g, out);
  k_tcn<<<1088, 256, 0, stream>>>(g, w1, gamma1, beta1, w2, gamma2, beta2, out);
}

// Round 2
// 551.692 us; speedup vs baseline: 1.1522x; 1.1522x over previous
//
#include <hip/hip_runtime.h>
#include <math.h>

typedef float f32x4 __attribute__((ext_vector_type(4)));

// Problem constants: B=64, N=17, T=512, C=64, H=4, DK=16
#define SLAB 32768           // per-(b,n) elems = T*C
#define BSLAB 557056         // per-b elems = N*T*C

__device__ __forceinline__ float gelu_exact(float x) {
  return 0.5f * x * (1.0f + erff(x * 0.7071067811865475f));
}

// ---------------------------------------------------------------------------
// K12: fused GEMM + GAT, wave-per-t. Block = 256 threads = 4 waves; wave w
// handles t = (blockIdx&127)*4 + w of b = blockIdx>>7. Each wave works in a
// PRIVATE LDS slice -> no __syncthreads after the initial adjs/av load (wave
// lockstep + compiler lgkmcnt ordering covers intra-wave LDS dependencies).
//   GEMM: hs[n][o=lane] = xs[n][:] . W[o][:], W row in 16 f32x4 VGPRs.
//   Attention: 68 (n,h) items on 64 lanes (1 full + 1 tiny iteration).
//   Two-pass softmax/colsum (no alpha array): pass1 stores per-row max m_i
//   and 1/S_i; pass2 recomputes exp(e_ij - m_i)/S_i -> bit-identical alphas.
// Writes g = h*scale + h0 (workspace) and permuted residual resP (d_out):
//   resP[b, n, t, c] = x[b, m%17, t, m/17], m = n*64+c.
// ---------------------------------------------------------------------------
__global__ __launch_bounds__(256) void k_gatgemm(const float* __restrict__ X,
                                                 const float* __restrict__ W,
                                                 const int* __restrict__ adj,
                                                 const float* __restrict__ avec,
                                                 float* __restrict__ g,
                                                 float* __restrict__ resP) {
  const int tid = threadIdx.x;
  const int lane = tid & 63, wv = tid >> 6;
  const int b = blockIdx.x >> 7;
  const int t = ((blockIdx.x & 127) << 2) | wv;

  __shared__ float xsA[4][17 * 68];   // per-wave h0 tile (X)
  __shared__ float hsA[4][17 * 68];   // per-wave GEMM output
  __shared__ float smA[4][272];       // per-wave: sv[68] tv[68] m[68] sinv[68]
  __shared__ float scA[4][68];        // per-wave scale
  __shared__ float av[32];
  __shared__ int adjs[289];

  float* xs = xsA[wv];
  float* hs = hsA[wv];
  float* sv = smA[wv];
  float* tv = sv + 68;
  float* mrow = sv + 136;
  float* sinv = sv + 204;
  float* scalev = scA[wv];

  const long base = (long)b * BSLAB + (long)t * 64;

  // shared (block-wide) small loads
  if (tid < 32) av[tid] = avec[tid];
  for (int idx = tid; idx < 289; idx += 256) adjs[idx] = adj[b * 289 + idx];

  // stage X[b,:,t,:]: 17 coalesced 256B loads, issued together for ILP
  float xr[17];
#pragma unroll
  for (int n = 0; n < 17; ++n) xr[n] = X[base + (long)n * SLAB + lane];

  // W row (o = lane) into 16 f32x4 registers (L1/L2-hot, 16 KB total)
  f32x4 wr[16];
  {
    const float* wrow = W + lane * 64;
#pragma unroll
    for (int k = 0; k < 16; ++k) wr[k] = *(const f32x4*)(wrow + k * 4);
  }

#pragma unroll
  for (int n = 0; n < 17; ++n) xs[n * 68 + lane] = xr[n];

  __syncthreads();   // the ONLY barrier: publishes av/adjs to all waves

  // ---- GEMM: hs[n][lane] = xs[n][:] . W[lane][:] (broadcast LDS reads) ----
#pragma unroll
  for (int n = 0; n < 17; ++n) {
    float acc = 0.f;
#pragma unroll
    for (int c4 = 0; c4 < 16; ++c4) {
      f32x4 xv = *(const f32x4*)(xs + n * 68 + c4 * 4);
      acc = fmaf(xv.x, wr[c4].x, acc);
      acc = fmaf(xv.y, wr[c4].y, acc);
      acc = fmaf(xv.z, wr[c4].z, acc);
      acc = fmaf(xv.w, wr[c4].w, acc);
    }
    hs[n * 68 + lane] = acc;   // banks (4n+lane)%32: all-distinct, free
  }

  // ---- s/t terms: 68 (n,h) items on 64 lanes ----
#pragma unroll
  for (int it = 0; it < 2; ++it) {
    int item = lane + it * 64;
    if (item < 68) {
      int n = item >> 2, h = item & 3;
      float s = 0.f, tt = 0.f;
#pragma unroll
      for (int d = 0; d < 16; ++d) {
        float hv = hs[n * 68 + h * 16 + d];
        s += hv * av[d];
        tt += hv * av[16 + d];
      }
      sv[item] = s;
      tv[item] = tt;
    }
  }

  // ---- softmax pass 1: per-row (i,h) max and 1/sum ----
#pragma unroll
  for (int it = 0; it < 2; ++it) {
    int item = lane + it * 64;
    if (item < 68) {
      int i = item >> 2, h = item & 3;
      float si = sv[item];
      float e[17];
      float mx = -3.4e38f;
#pragma unroll
      for (int j = 0; j < 17; ++j) {
        float v = si + tv[j * 4 + h];
        v = (v >= 0.f) ? v : 0.2f * v;           // leaky_relu(0.2)
        if (adjs[i * 17 + j] == 0) v += -1e9f;   // mask bias after lrelu
        e[j] = v;
        mx = fmaxf(mx, v);
      }
      float sum = 0.f;
#pragma unroll
      for (int j = 0; j < 17; ++j) sum += expf(e[j] - mx);
      mrow[item] = mx;
      sinv[item] = 1.0f / sum;
    }
  }

  // ---- pass 2: scale[j,h] = sum_i alpha[i,j,h] (recomputed, bit-identical)
#pragma unroll
  for (int it = 0; it < 2; ++it) {
    int item = lane + it * 64;
    if (item < 68) {
      int j = item >> 2, h = item & 3;
      float tj = tv[item];
      float sc = 0.f;
#pragma unroll
      for (int i = 0; i < 17; ++i) {
        float v = sv[i * 4 + h] + tj;
        v = (v >= 0.f) ? v : 0.2f * v;
        if (adjs[i * 17 + j] == 0) v += -1e9f;
        sc += expf(v - mrow[i * 4 + h]) * sinv[i * 4 + h];
      }
      scalev[item] = sc;
    }
  }

  // ---- final: g = h*scale + h0, resP = permuted x ----
#pragma unroll
  for (int n = 0; n < 17; ++n) {
    long a = base + (long)n * SLAB + lane;
    int m = n * 64 + lane;
    g[a] = hs[n * 68 + lane] * scalev[n * 4 + (lane >> 4)] + xs[n * 68 + lane];
    resP[a] = xs[(m % 17) * 68 + (m / 17)];
  }
}

// ---------------------------------------------------------------------------
// K3: TCN (2x causal depthwise conv + eval-BN + exact GELU) + transpose +
// residual add. One block per (b,n). g's per-(b,n) flat [T,C] block IS the
// conv layout [c'=idx>>9][t'=idx&511]. Processed in two t-halves of 256
// (LDS 64x257 fp32 = 64.3 KB -> 2 blocks/CU). Thread (cc=tid>>2, q=tid&3)
// convs t' in [q*128, q*128+128) during half q>>1 (lead-in from global g).
// resP lives in d_out; final out overwrites it same-thread same-address.
// [Reverted to the round-0 verified 191 us version.]
// ---------------------------------------------------------------------------
__global__ __launch_bounds__(256) void k_tcn(const float* __restrict__ g,
                                             const float* __restrict__ w1,
                                             const float* __restrict__ gamma1,
                                             const float* __restrict__ beta1,
                                             const float* __restrict__ w2,
                                             const float* __restrict__ gamma2,
                                             const float* __restrict__ beta2,
                                             float* __restrict__ out) {
  const int bn = blockIdx.x;
  const int tid = threadIdx.x;
  const int cc = tid >> 2, q = tid & 3;

  __shared__ float L[64 * 257];

  const long gbase = (long)bn * SLAB + cc * 512;
  const long obase = (long)bn * SLAB;

  const float bnmul = 0.9999950000374997f;  // 1/sqrt(1+1e-5)
  const float w10 = w1[cc * 3 + 0], w11 = w1[cc * 3 + 1], w12 = w1[cc * 3 + 2];
  const float w20 = w2[cc * 3 + 0], w21 = w2[cc * 3 + 1], w22 = w2[cc * 3 + 2];
  const float bs1 = gamma1[cc] * bnmul, bb1 = beta1[cc];
  const float bs2 = gamma2[cc] * bnmul, bb2 = beta2[cc];

  const int t0 = q * 128;

  for (int h = 0; h < 2; ++h) {
    if ((q >> 1) == h) {
      float gm1 = 0.f, gm2 = 0.f;
      float zm1 = 0.f, zm2 = 0.f, zm3 = 0.f, zm4 = 0.f;
      if (q > 0) {
        float gg[6];
#pragma unroll
        for (int k = 0; k < 6; ++k) gg[k] = g[gbase + (t0 - 6 + k)];
        zm4 = gelu_exact((w10 * gg[0] + w11 * gg[1] + w12 * gg[2]) * bs1 + bb1);
        zm3 = gelu_exact((w10 * gg[1] + w11 * gg[2] + w12 * gg[3]) * bs1 + bb1);
        zm2 = gelu_exact((w10 * gg[2] + w11 * gg[3] + w12 * gg[4]) * bs1 + bb1);
        zm1 = gelu_exact((w10 * gg[3] + w11 * gg[4] + w12 * gg[5]) * bs1 + bb1);
        gm2 = gg[4];
        gm1 = gg[5];
      }
      for (int blk = 0; blk < 32; ++blk) {
        f32x4 gv4 = *(const f32x4*)(g + gbase + t0 + blk * 4);
#pragma unroll
        for (int j = 0; j < 4; ++j) {
          float gv = gv4[j];
          float z = gelu_exact((w10 * gm2 + w11 * gm1 + w12 * gv) * bs1 + bb1);
          float y = gelu_exact((w20 * zm4 + w21 * zm2 + w22 * z) * bs2 + bb2);
          L[cc * 257 + (t0 + blk * 4 + j - h * 256)] = y;
          gm2 = gm1; gm1 = gv;
          zm4 = zm3; zm3 = zm2; zm2 = zm1; zm1 = z;
        }
      }
    }
    __syncthreads();

    // transpose + residual for out flat range [h*16384, h*16384+16384)
    for (int k = 0; k < 16; ++k) {
      int f4 = h * 4096 + tid + k * 256;
      int flat = f4 * 4;
      int t = flat >> 6, c0 = flat & 63;
      f32x4 r4 = *(const f32x4*)(out + obase + flat);
      f32x4 o4;
#pragma unroll
      for (int j = 0; j < 4; ++j)
        o4[j] = L[(c0 + j) * 257 + (t - h * 256)] + r4[j];
      *(f32x4*)(out + obase + flat) = o4;
    }
    __syncthreads();
  }
}

// ---------------------------------------------------------------------------
extern "C" void kernel_launch(void* const* d_in, const int* in_sizes, int n_in,
                              void* d_out, int out_size, void* d_ws, size_t ws_size,
                              hipStream_t stream) {
  const float* x = (const float*)d_in[0];
  const int* adj = (const int*)d_in[1];
  const float* W = (const float*)d_in[2];
  const float* avec = (const float*)d_in[3];
  const float* w1 = (const float*)d_in[4];
  const float* gamma1 = (const float*)d_in[5];
  const float* beta1 = (const float*)d_in[6];
  const float* w2 = (const float*)d_in[7];
  const float* gamma2 = (const float*)d_in[8];
  const float* beta2 = (const float*)d_in[9];

  float* g = (float*)d_ws;       // 142.6 MB scratch: GAT output / TCN input
  float* out = (float*)d_out;    // resP written by K12, consumed in-place by K3

  k_gatgemm<<<8192, 256, 0, stream>>>(x, W, adj, avec, g, out);
  k_tcn<<<1088, 256, 0, stream>>>(g, w1, gamma1, beta1, w2, gamma2, beta2, out);
}

// Round 4
// 464.830 us; speedup vs baseline: 1.3675x; 1.1869x over previous
//
#include <hip/hip_runtime.h>
#include <math.h>

typedef float f32x4 __attribute__((ext_vector_type(4)));

// Problem constants: B=64, N=17, T=512, C=64, H=4, DK=16
#define SLAB 32768           // per-(b,n) elems = T*C
#define BSLAB 557056         // per-b elems = N*T*C

__device__ __forceinline__ float gelu_exact(float x) {
  return 0.5f * x * (1.0f + erff(x * 0.7071067811865475f));
}

// ---------------------------------------------------------------------------
// K12: fused GEMM + GAT, wave-per-t. Block = 256 threads = 4 waves; wave w
// handles t = (blockIdx&127)*4 + w of b = blockIdx>>7. Each wave works in a
// PRIVATE LDS slice -> no __syncthreads after the initial adjs/av load (wave
// lockstep + compiler lgkmcnt ordering covers intra-wave LDS dependencies).
//   GEMM: hs[n][o=lane] = xs[n][:] . W[o][:], W row in 16 f32x4 VGPRs.
//   Attention: 68 (n,h) items on 64 lanes (1 full + 1 tiny iteration).
//   Two-pass softmax/colsum (no alpha array): pass1 stores per-row max m_i
//   and 1/S_i; pass2 recomputes exp(e_ij - m_i)/S_i (same __expf both passes
//   -> identical alpha values).
//   exp via __expf (v_exp_f32): rel err ~1e-6, removes ~25-inst ocml expf
//   from the VALU-bound critical path (68 calls/lane).
// Writes g = h*scale + h0 (workspace) and permuted residual resP (d_out):
//   resP[b, n, t, c] = x[b, m%17, t, m/17], m = n*64+c.
// ---------------------------------------------------------------------------
__global__ __launch_bounds__(256) void k_gatgemm(const float* __restrict__ X,
                                                 const float* __restrict__ W,
                                                 const int* __restrict__ adj,
                                                 const float* __restrict__ avec,
                                                 float* __restrict__ g,
                                                 float* __restrict__ resP) {
  const int tid = threadIdx.x;
  const int lane = tid & 63, wv = tid >> 6;
  const int b = blockIdx.x >> 7;
  const int t = ((blockIdx.x & 127) << 2) | wv;

  __shared__ float xsA[4][17 * 68];   // per-wave h0 tile (X)
  __shared__ float hsA[4][17 * 68];   // per-wave GEMM output
  __shared__ float smA[4][272];       // per-wave: sv[68] tv[68] m[68] sinv[68]
  __shared__ float scA[4][68];        // per-wave scale
  __shared__ float av[32];
  __shared__ int adjs[289];

  float* xs = xsA[wv];
  float* hs = hsA[wv];
  float* sv = smA[wv];
  float* tv = sv + 68;
  float* mrow = sv + 136;
  float* sinv = sv + 204;
  float* scalev = scA[wv];

  const long base = (long)b * BSLAB + (long)t * 64;

  // shared (block-wide) small loads
  if (tid < 32) av[tid] = avec[tid];
  for (int idx = tid; idx < 289; idx += 256) adjs[idx] = adj[b * 289 + idx];

  // stage X[b,:,t,:]: 17 coalesced 256B loads, issued together for ILP
  float xr[17];
#pragma unroll
  for (int n = 0; n < 17; ++n) xr[n] = X[base + (long)n * SLAB + lane];

  // W row (o = lane) into 16 f32x4 registers (L1/L2-hot, 16 KB total)
  f32x4 wr[16];
  {
    const float* wrow = W + lane * 64;
#pragma unroll
    for (int k = 0; k < 16; ++k) wr[k] = *(const f32x4*)(wrow + k * 4);
  }

#pragma unroll
  for (int n = 0; n < 17; ++n) xs[n * 68 + lane] = xr[n];

  __syncthreads();   // the ONLY barrier: publishes av/adjs to all waves

  // ---- GEMM: hs[n][lane] = xs[n][:] . W[lane][:] (broadcast LDS reads) ----
#pragma unroll
  for (int n = 0; n < 17; ++n) {
    float acc = 0.f;
#pragma unroll
    for (int c4 = 0; c4 < 16; ++c4) {
      f32x4 xv = *(const f32x4*)(xs + n * 68 + c4 * 4);
      acc = fmaf(xv.x, wr[c4].x, acc);
      acc = fmaf(xv.y, wr[c4].y, acc);
      acc = fmaf(xv.z, wr[c4].z, acc);
      acc = fmaf(xv.w, wr[c4].w, acc);
    }
    hs[n * 68 + lane] = acc;   // banks (4n+lane)%32: all-distinct, free
  }

  // ---- s/t terms: 68 (n,h) items on 64 lanes ----
#pragma unroll
  for (int it = 0; it < 2; ++it) {
    int item = lane + it * 64;
    if (item < 68) {
      int n = item >> 2, h = item & 3;
      float s = 0.f, tt = 0.f;
#pragma unroll
      for (int d = 0; d < 16; ++d) {
        float hv = hs[n * 68 + h * 16 + d];
        s += hv * av[d];
        tt += hv * av[16 + d];
      }
      sv[item] = s;
      tv[item] = tt;
    }
  }

  // ---- softmax pass 1: per-row (i,h) max and 1/sum ----
#pragma unroll
  for (int it = 0; it < 2; ++it) {
    int item = lane + it * 64;
    if (item < 68) {
      int i = item >> 2, h = item & 3;
      float si = sv[item];
      float e[17];
      float mx = -3.4e38f;
#pragma unroll
      for (int j = 0; j < 17; ++j) {
        float v = si + tv[j * 4 + h];
        v = (v >= 0.f) ? v : 0.2f * v;           // leaky_relu(0.2)
        if (adjs[i * 17 + j] == 0) v += -1e9f;   // mask bias after lrelu
        e[j] = v;
        mx = fmaxf(mx, v);
      }
      float sum = 0.f;
#pragma unroll
      for (int j = 0; j < 17; ++j) sum += __expf(e[j] - mx);
      mrow[item] = mx;
      sinv[item] = 1.0f / sum;
    }
  }

  // ---- pass 2: scale[j,h] = sum_i alpha[i,j,h] (recomputed) ----
#pragma unroll
  for (int it = 0; it < 2; ++it) {
    int item = lane + it * 64;
    if (item < 68) {
      int j = item >> 2, h = item & 3;
      float tj = tv[item];
      float sc = 0.f;
#pragma unroll
      for (int i = 0; i < 17; ++i) {
        float v = sv[i * 4 + h] + tj;
        v = (v >= 0.f) ? v : 0.2f * v;
        if (adjs[i * 17 + j] == 0) v += -1e9f;
        sc += __expf(v - mrow[i * 4 + h]) * sinv[i * 4 + h];
      }
      scalev[item] = sc;
    }
  }

  // ---- final: g = h*scale + h0, resP = permuted x ----
#pragma unroll
  for (int n = 0; n < 17; ++n) {
    long a = base + (long)n * SLAB + lane;
    int m = n * 64 + lane;
    g[a] = hs[n * 68 + lane] * scalev[n * 4 + (lane >> 4)] + xs[n * 68 + lane];
    resP[a] = xs[(m % 17) * 68 + (m / 17)];
  }
}

// ---------------------------------------------------------------------------
// K3: TCN (2x causal depthwise conv + eval-BN + exact GELU) + transpose +
// residual add. t-QUARTER split: block = (bn, Q), Q in [0,4), owns
// t in [Q*128, Q*128+128) for ALL 64 channels -> the out[t][c] = y[c][t]
// transpose is block-local and the block's out range is one dense 32 KB
// span (perfectly coalesced read-modify-write of the resP residual).
// Thread (c = tid&63, sq = tid>>6) convs t in [t0, t0+32), t0 = Q*128+sq*32,
// with the 6-value lead-in recomputed from global g (exact: z[t<0]=0).
// LDS L[128][68] ([t_local][c], pitch 68) = 34 KB -> 4 blocks/CU, ONE barrier,
// all 256 threads active.
//   conv write  L[tl*68 + c]: bank (4tl + lane)%32 -> exact 2-way, free.
//   b128 read   L[tl*68 + c0]: consecutive 8 lanes hit 8 disjoint bank-quads.
// resP lives in d_out; out overwrites it same-address (disjoint per block).
// ---------------------------------------------------------------------------
__global__ __launch_bounds__(256) void k_tcn(const float* __restrict__ g,
                                             const float* __restrict__ w1,
                                             const float* __restrict__ gamma1,
                                             const float* __restrict__ beta1,
                                             const float* __restrict__ w2,
                                             const float* __restrict__ gamma2,
                                             const float* __restrict__ beta2,
                                             float* __restrict__ out) {
  const int bn = blockIdx.x >> 2;
  const int Q = blockIdx.x & 3;
  const int tid = threadIdx.x;
  const int c = tid & 63;        // conv channel (= lane)
  const int sq = tid >> 6;       // sub-quarter (= wave id)

  __shared__ float L[128 * 68];  // [t_local][c], 34816 B

  const long gbase = (long)bn * SLAB + c * 512;
  const long obase = (long)bn * SLAB;

  const float bnmul = 0.9999950000374997f;  // 1/sqrt(1+1e-5)
  const float w10 = w1[c * 3 + 0], w11 = w1[c * 3 + 1], w12 = w1[c * 3 + 2];
  const float w20 = w2[c * 3 + 0], w21 = w2[c * 3 + 1], w22 = w2[c * 3 + 2];
  const float bs1 = gamma1[c] * bnmul, bb1 = beta1[c];
  const float bs2 = gamma2[c] * bnmul, bb2 = beta2[c];

  const int t0 = Q * 128 + sq * 32;
  const int tl0 = sq * 32;

  // lead-in state: gm* = raw g, zm* = conv1+BN+GELU outputs (z[t<0] == 0
  // exactly: reference zero-pads z before conv2)
  float gm1 = 0.f, gm2 = 0.f;
  float zm1 = 0.f, zm2 = 0.f, zm3 = 0.f, zm4 = 0.f;
  if (t0 > 0) {
    float gg[6];
#pragma unroll
    for (int k = 0; k < 6; ++k) gg[k] = g[gbase + (t0 - 6 + k)];
    zm4 = gelu_exact((w10 * gg[0] + w11 * gg[1] + w12 * gg[2]) * bs1 + bb1);
    zm3 = gelu_exact((w10 * gg[1] + w11 * gg[2] + w12 * gg[3]) * bs1 + bb1);
    zm2 = gelu_exact((w10 * gg[2] + w11 * gg[3] + w12 * gg[4]) * bs1 + bb1);
    zm1 = gelu_exact((w10 * gg[3] + w11 * gg[4] + w12 * gg[5]) * bs1 + bb1);
    gm2 = gg[4];
    gm1 = gg[5];
  }

  for (int blk = 0; blk < 8; ++blk) {
    f32x4 gv4 = *(const f32x4*)(g + gbase + t0 + blk * 4);
#pragma unroll
    for (int j = 0; j < 4; ++j) {
      float gv = gv4[j];
      float z = gelu_exact((w10 * gm2 + w11 * gm1 + w12 * gv) * bs1 + bb1);
      float y = gelu_exact((w20 * zm4 + w21 * zm2 + w22 * z) * bs2 + bb2);
      L[(tl0 + blk * 4 + j) * 68 + c] = y;
      gm2 = gm1; gm1 = gv;
      zm4 = zm3; zm3 = zm2; zm2 = zm1; zm1 = z;
    }
  }
  __syncthreads();

  // transpose + residual: out[t][c] = L[t - Q*128][c] + resP[t][c],
  // flat range [Q*8192, Q*8192+8192) — dense, fully coalesced.
  for (int k = 0; k < 8; ++k) {
    int f4 = tid + k * 256;            // local chunk id, 0..2047
    int flat = Q * 8192 + f4 * 4;
    int tl = f4 >> 4;                  // t - Q*128
    int c0 = (f4 & 15) * 4;
    f32x4 l4 = *(const f32x4*)(L + tl * 68 + c0);
    f32x4 r4 = *(const f32x4*)(out + obase + flat);
    f32x4 o4;
#pragma unroll
    for (int j = 0; j < 4; ++j) o4[j] = l4[j] + r4[j];
    *(f32x4*)(out + obase + flat) = o4;
  }
}

// ---------------------------------------------------------------------------
extern "C" void kernel_launch(void* const* d_in, const int* in_sizes, int n_in,
                              void* d_out, int out_size, void* d_ws, size_t ws_size,
                              hipStream_t stream) {
  const float* x = (const float*)d_in[0];
  const int* adj = (const int*)d_in[1];
  const float* W = (const float*)d_in[2];
  const float* avec = (const float*)d_in[3];
  const float* w1 = (const float*)d_in[4];
  const float* gamma1 = (const float*)d_in[5];
  const float* beta1 = (const float*)d_in[6];
  const float* w2 = (const float*)d_in[7];
  const float* gamma2 = (const float*)d_in[8];
  const float* beta2 = (const float*)d_in[9];

  float* g = (float*)d_ws;       // 142.6 MB scratch: GAT output / TCN input
  float* out = (float*)d_out;    // resP written by K12, consumed in-place by K3

  k_gatgemm<<<8192, 256, 0, stream>>>(x, W, adj, avec, g, out);
  k_tcn<<<4352, 256, 0, stream>>>(g, w1, gamma1, beta1, w2, gamma2, beta2, out);
}